// Round 1
// baseline (289.301 us; speedup 1.0000x reference)
//
#include <hip/hip_runtime.h>
#include <math.h>

// Problem constants
#define NB 16
#define NT 200
#define ND 128
#define NH 4
#define NDK 32

// ---------------------------------------------------------------------------
// Kernel 1: fused QKV projection.  q = query@Wq+bq etc.  4 rows per block.
// ---------------------------------------------------------------------------
__global__ __launch_bounds__(128) void qkv_proj_k(
    const float* __restrict__ query, const float* __restrict__ key_,
    const float* __restrict__ value,
    const float* __restrict__ Wq, const float* __restrict__ bq,
    const float* __restrict__ Wk, const float* __restrict__ bk,
    const float* __restrict__ Wv, const float* __restrict__ bv,
    float* __restrict__ qp, float* __restrict__ kp, float* __restrict__ vp)
{
    __shared__ float xq[4][128], xk[4][128], xv[4][128];
    int t = threadIdx.x;
    int g0 = blockIdx.x * 4;
    for (int r = 0; r < 4; ++r) {
        xq[r][t] = query[(size_t)(g0 + r) * ND + t];
        xk[r][t] = key_ [(size_t)(g0 + r) * ND + t];
        xv[r][t] = value[(size_t)(g0 + r) * ND + t];
    }
    __syncthreads();
    float aq[4], ak[4], av[4];
    for (int r = 0; r < 4; ++r) { aq[r] = bq[t]; ak[r] = bk[t]; av[r] = bv[t]; }
    for (int d = 0; d < 128; ++d) {
        float wq = Wq[d * ND + t], wk = Wk[d * ND + t], wv = Wv[d * ND + t];
        #pragma unroll
        for (int r = 0; r < 4; ++r) {
            aq[r] += xq[r][d] * wq;
            ak[r] += xk[r][d] * wk;
            av[r] += xv[r][d] * wv;
        }
    }
    for (int r = 0; r < 4; ++r) {
        qp[(size_t)(g0 + r) * ND + t] = aq[r];
        kp[(size_t)(g0 + r) * ND + t] = ak[r];
        vp[(size_t)(g0 + r) * ND + t] = av[r];
    }
}

// ---------------------------------------------------------------------------
// Kernel 2: abs-head prep.  qa = Xq_a + Pq, ka = Xk_a + Pk.
// 8 (b,i) rows per block; 128 threads = which(2) x h(2) x o(32).
// ---------------------------------------------------------------------------
__global__ __launch_bounds__(128) void abs_prep_k(
    const float* __restrict__ absk,
    const float* __restrict__ aqw, const float* __restrict__ aqb,
    const float* __restrict__ akw, const float* __restrict__ akb,
    const float* __restrict__ qp, const float* __restrict__ kp,
    float* __restrict__ qa, float* __restrict__ ka)
{
    __shared__ float aks[8][2][128];
    int t = threadIdx.x;
    int g0 = blockIdx.x * 8;
    for (int idx = t; idx < 8 * 2 * 128; idx += 128) {
        int r  = idx >> 8;          // /256
        int h2 = (idx >> 7) & 1;
        int d  = idx & 127;
        int g = g0 + r; int b = g / NT; int i = g % NT;
        aks[r][h2][d] = absk[(((size_t)h2 * NB + b) * NT + i) * ND + d];
    }
    __syncthreads();
    int which = t >> 6;         // 0 = q side, 1 = k side
    int h = (t >> 5) & 1;
    int o = t & 31;
    const float* w  = which ? akw : aqw;
    const float* bb = which ? akb : aqb;
    const float* xp = which ? kp  : qp;
    float bv = bb[h * NDK + o];
    float acc[8];
    for (int r = 0; r < 8; ++r) acc[r] = bv;
    for (int d = 0; d < 128; ++d) {
        float wv = w[((size_t)h * ND + d) * NDK + o];
        #pragma unroll
        for (int r = 0; r < 8; ++r) acc[r] += aks[r][h][d] * wv;
    }
    float* dst = which ? ka : qa;
    for (int r = 0; r < 8; ++r) {
        int g = g0 + r; int b = g / NT; int i = g % NT;
        float val = acc[r] + xp[(size_t)g * ND + h * NDK + o];
        dst[((size_t)(b * 2 + h) * NT + i) * NDK + o] = val;
    }
}

// ---------------------------------------------------------------------------
// Kernel 3: rel-head prep.
// u[b,h,i,d] = sum_o (Xq_r[b,h,i,o]+rel_bias[h,o]) * rel_k_w[h,d,o]
// c[b,h,i]   = sum_o (Xq_r[b,h,i,o]+rel_bias[h,o]) * rel_k_b[h,o]
// 8 rows per block; 256 threads = h(2) x d(128).
// ---------------------------------------------------------------------------
__global__ __launch_bounds__(256) void rel_prep_k(
    const float* __restrict__ qp,
    const float* __restrict__ rkw, const float* __restrict__ rkb,
    const float* __restrict__ rbias,
    float* __restrict__ u, float* __restrict__ cb)
{
    __shared__ float qb[8][2][32];
    int t = threadIdx.x;
    int g0 = blockIdx.x * 8;
    for (int idx = t; idx < 8 * 2 * 32; idx += 256) {
        int r = idx >> 6; int h2 = (idx >> 5) & 1; int o = idx & 31;
        int g = g0 + r;
        qb[r][h2][o] = qp[(size_t)g * ND + (2 + h2) * NDK + o] + rbias[h2 * NDK + o];
    }
    __syncthreads();
    int h = t >> 7;     // 0..1
    int d = t & 127;
    float acc[8] = {0, 0, 0, 0, 0, 0, 0, 0};
    for (int o = 0; o < 32; ++o) {
        float wv = rkw[((size_t)h * ND + d) * NDK + o];
        #pragma unroll
        for (int r = 0; r < 8; ++r) acc[r] += qb[r][h][o] * wv;
    }
    for (int r = 0; r < 8; ++r) {
        int g = g0 + r; int b = g / NT; int i = g % NT;
        u[((size_t)(b * 2 + h) * NT + i) * ND + d] = acc[r];
    }
    if (d == 0) {
        for (int r = 0; r < 8; ++r) {
            float cc = 0.0f;
            for (int o = 0; o < 32; ++o) cc += qb[r][h][o] * rkb[h * NDK + o];
            int g = g0 + r; int b = g / NT; int i = g % NT;
            cb[(b * 2 + h) * NT + i] = cc;
        }
    }
}

// ---------------------------------------------------------------------------
// Kernel 4: fused scores + mask + softmax + PV.  One block per (b,h,i).
// Rel heads stream their 200x128 rel_kernel slice with half-wave float4 rows.
// ---------------------------------------------------------------------------
__global__ __launch_bounds__(256) void attn_core_k(
    const float* __restrict__ qp, const float* __restrict__ kp,
    const float* __restrict__ vp,
    const float* __restrict__ qa, const float* __restrict__ ka,
    const float* __restrict__ u,  const float* __restrict__ cb,
    const int* __restrict__ mask, const float* __restrict__ rel,
    float* __restrict__ xb)
{
    __shared__ float s[256];
    __shared__ float qrow[32];
    __shared__ float redm[4], reds[4];
    __shared__ float xred[256];
    int t = threadIdx.x;
    int bx = blockIdx.x;
    int i  = bx % NT;
    int bh = bx / NT;
    int h  = bh % NH;
    int b  = bh / NH;
    bool isrel = (h >= 2);
    int hr = h - 2;

    if (t < 32) {
        qrow[t] = isrel ? qp[((size_t)(b * NT + i)) * ND + h * NDK + t]
                        : qa[((size_t)(b * 2 + h) * NT + i) * NDK + t];
    }
    __syncthreads();

    float cval = isrel ? cb[(b * 2 + hr) * NT + i] : 0.0f;
    if (t < NT) {
        const float* krow = isrel ? (kp + ((size_t)(b * NT + t)) * ND + h * NDK)
                                  : (ka + ((size_t)(b * 2 + h) * NT + t) * NDK);
        const float4* k4 = (const float4*)krow;
        const float4* q4 = (const float4*)qrow;
        float acc = cval;
        #pragma unroll
        for (int q = 0; q < 8; ++q) {
            float4 kv = k4[q]; float4 qv = q4[q];
            acc += kv.x * qv.x + kv.y * qv.y + kv.z * qv.z + kv.w * qv.w;
        }
        s[t] = acc;
    } else {
        s[t] = -INFINITY;
    }
    __syncthreads();

    if (isrel) {
        int wid = t >> 6, lane = t & 63, half = lane >> 5, l32 = lane & 31;
        const float4* u4 = (const float4*)(u + ((size_t)(b * 2 + hr) * NT + i) * ND);
        float4 ur = u4[l32];
        const float* relbase =
            rel + ((((size_t)hr * NB + b) * NT + i) * (size_t)NT) * ND;
        for (int it = 0; it < 25; ++it) {
            int j = it * 8 + wid * 2 + half;
            const float4* r4 = (const float4*)(relbase + (size_t)j * ND);
            float4 rv = r4[l32];
            float acc = rv.x * ur.x + rv.y * ur.y + rv.z * ur.z + rv.w * ur.w;
            acc += __shfl_xor(acc, 16, 32);
            acc += __shfl_xor(acc, 8, 32);
            acc += __shfl_xor(acc, 4, 32);
            acc += __shfl_xor(acc, 2, 32);
            acc += __shfl_xor(acc, 1, 32);
            if (l32 == 0) s[j] += acc;
        }
        __syncthreads();
    }

    // scale then mask (matches reference order: scale, then where(mask==0,-1e9))
    if (t < NT) {
        float val = s[t] * 0.17677669529663687f;   // 1/sqrt(32)
        if (mask[((size_t)b * NT + i) * NT + t] == 0) val = -1.0e9f;
        s[t] = val;
    }
    __syncthreads();

    // softmax over 256 slots (pad = -inf -> exp 0)
    float sv = s[t];
    float m = sv;
    #pragma unroll
    for (int dd = 32; dd >= 1; dd >>= 1) m = fmaxf(m, __shfl_xor(m, dd, 64));
    if ((t & 63) == 0) redm[t >> 6] = m;
    __syncthreads();
    m = fmaxf(fmaxf(redm[0], redm[1]), fmaxf(redm[2], redm[3]));
    float e = expf(sv - m);
    float ssum = e;
    #pragma unroll
    for (int dd = 32; dd >= 1; dd >>= 1) ssum += __shfl_xor(ssum, dd, 64);
    if ((t & 63) == 0) reds[t >> 6] = ssum;
    __syncthreads();
    float tot = reds[0] + reds[1] + reds[2] + reds[3];
    s[t] = e / tot;
    __syncthreads();

    // PV: x[o] = sum_j p[j] * v[b, j, h*32+o]
    int o = t & 31, g = t >> 5;
    float acc2 = 0.0f;
    const float* vb = vp + (size_t)b * NT * ND + h * NDK + o;
    for (int j = g; j < NT; j += 8) acc2 += s[j] * vb[(size_t)j * ND];
    xred[t] = acc2;
    __syncthreads();
    if (t < 32) {
        float r = 0.0f;
        #pragma unroll
        for (int g2 = 0; g2 < 8; ++g2) r += xred[g2 * 32 + t];
        xb[((size_t)(b * NT + i)) * ND + h * NDK + t] = r;
    }
}

// ---------------------------------------------------------------------------
// Kernel 5: output projection.  out = xb @ Wo + bo.
// ---------------------------------------------------------------------------
__global__ __launch_bounds__(128) void out_proj_k(
    const float* __restrict__ xb, const float* __restrict__ Wo,
    const float* __restrict__ bo, float* __restrict__ out)
{
    __shared__ float xs[4][128];
    int t = threadIdx.x;
    int g0 = blockIdx.x * 4;
    for (int r = 0; r < 4; ++r) xs[r][t] = xb[(size_t)(g0 + r) * ND + t];
    __syncthreads();
    float bb = bo[t];
    float acc[4];
    for (int r = 0; r < 4; ++r) acc[r] = bb;
    for (int d = 0; d < 128; ++d) {
        float wv = Wo[d * ND + t];
        #pragma unroll
        for (int r = 0; r < 4; ++r) acc[r] += xs[r][d] * wv;
    }
    for (int r = 0; r < 4; ++r) out[(size_t)(g0 + r) * ND + t] = acc[r];
}

// ---------------------------------------------------------------------------
extern "C" void kernel_launch(void* const* d_in, const int* in_sizes, int n_in,
                              void* d_out, int out_size, void* d_ws, size_t ws_size,
                              hipStream_t stream)
{
    const float* query = (const float*)d_in[0];
    const float* key_  = (const float*)d_in[1];
    const float* value = (const float*)d_in[2];
    const int*   mask  = (const int*)  d_in[3];
    const float* rel   = (const float*)d_in[4];
    const float* absk  = (const float*)d_in[5];
    // d_in[6] = layer (unused by reference)
    const float* Wq = (const float*)d_in[7];
    const float* bq = (const float*)d_in[8];
    const float* Wk = (const float*)d_in[9];
    const float* bk = (const float*)d_in[10];
    const float* Wv = (const float*)d_in[11];
    const float* bv = (const float*)d_in[12];
    const float* aqw = (const float*)d_in[13];
    const float* aqb = (const float*)d_in[14];
    const float* akw = (const float*)d_in[15];
    const float* akb = (const float*)d_in[16];
    const float* rkw = (const float*)d_in[17];
    const float* rkb = (const float*)d_in[18];
    const float* rbias = (const float*)d_in[19];
    const float* Wo = (const float*)d_in[20];
    const float* bo = (const float*)d_in[21];
    float* out = (float*)d_out;

    // workspace layout (floats)
    float* qp = (float*)d_ws;          // 409600  (B,T,D)
    float* kp = qp + 409600;           // 409600
    float* vp = kp + 409600;           // 409600
    float* qa = vp + 409600;           // 204800  (B,2,T,32)
    float* ka = qa + 204800;           // 204800
    float* ub = ka + 204800;           // 819200  (B,2,T,128)
    float* cb = ub + 819200;           // 6400    (B,2,T)
    float* xb = cb + 6400;             // 409600  (B,T,D)
    // total ~11.5 MB

    qkv_proj_k<<<NB * NT / 4, 128, 0, stream>>>(query, key_, value,
                                                Wq, bq, Wk, bk, Wv, bv,
                                                qp, kp, vp);
    abs_prep_k<<<NB * NT / 8, 128, 0, stream>>>(absk, aqw, aqb, akw, akb,
                                                qp, kp, qa, ka);
    rel_prep_k<<<NB * NT / 8, 256, 0, stream>>>(qp, rkw, rkb, rbias, ub, cb);
    attn_core_k<<<NB * NH * NT, 256, 0, stream>>>(qp, kp, vp, qa, ka, ub, cb,
                                                  mask, rel, xb);
    out_proj_k<<<NB * NT / 4, 128, 0, stream>>>(xb, Wo, bo, out);
}

// Round 2
// 235.675 us; speedup vs baseline: 1.2275x; 1.2275x over previous
//
#include <hip/hip_runtime.h>
#include <math.h>

// Problem constants
#define NB 16
#define NT 200
#define ND 128
#define NH 4
#define NDK 32

typedef float f32x4 __attribute__((ext_vector_type(4)));

// ---------------------------------------------------------------------------
// Kernel 1: fused QKV projection.  q = query@Wq+bq etc.  4 rows per block.
// ---------------------------------------------------------------------------
__global__ __launch_bounds__(128) void qkv_proj_k(
    const float* __restrict__ query, const float* __restrict__ key_,
    const float* __restrict__ value,
    const float* __restrict__ Wq, const float* __restrict__ bq,
    const float* __restrict__ Wk, const float* __restrict__ bk,
    const float* __restrict__ Wv, const float* __restrict__ bv,
    float* __restrict__ qp, float* __restrict__ kp, float* __restrict__ vp)
{
    __shared__ float xq[4][128], xk[4][128], xv[4][128];
    int t = threadIdx.x;
    int g0 = blockIdx.x * 4;
    for (int r = 0; r < 4; ++r) {
        xq[r][t] = query[(size_t)(g0 + r) * ND + t];
        xk[r][t] = key_ [(size_t)(g0 + r) * ND + t];
        xv[r][t] = value[(size_t)(g0 + r) * ND + t];
    }
    __syncthreads();
    float aq[4], ak[4], av[4];
    for (int r = 0; r < 4; ++r) { aq[r] = bq[t]; ak[r] = bk[t]; av[r] = bv[t]; }
    for (int d = 0; d < 128; ++d) {
        float wq = Wq[d * ND + t], wk = Wk[d * ND + t], wv = Wv[d * ND + t];
        #pragma unroll
        for (int r = 0; r < 4; ++r) {
            aq[r] += xq[r][d] * wq;
            ak[r] += xk[r][d] * wk;
            av[r] += xv[r][d] * wv;
        }
    }
    for (int r = 0; r < 4; ++r) {
        qp[(size_t)(g0 + r) * ND + t] = aq[r];
        kp[(size_t)(g0 + r) * ND + t] = ak[r];
        vp[(size_t)(g0 + r) * ND + t] = av[r];
    }
}

// ---------------------------------------------------------------------------
// Kernel 2: abs-head prep.  qa = Xq_a + Pq, ka = Xk_a + Pk.
// ---------------------------------------------------------------------------
__global__ __launch_bounds__(128) void abs_prep_k(
    const float* __restrict__ absk,
    const float* __restrict__ aqw, const float* __restrict__ aqb,
    const float* __restrict__ akw, const float* __restrict__ akb,
    const float* __restrict__ qp, const float* __restrict__ kp,
    float* __restrict__ qa, float* __restrict__ ka)
{
    __shared__ float aks[8][2][128];
    int t = threadIdx.x;
    int g0 = blockIdx.x * 8;
    for (int idx = t; idx < 8 * 2 * 128; idx += 128) {
        int r  = idx >> 8;
        int h2 = (idx >> 7) & 1;
        int d  = idx & 127;
        int g = g0 + r; int b = g / NT; int i = g % NT;
        aks[r][h2][d] = absk[(((size_t)h2 * NB + b) * NT + i) * ND + d];
    }
    __syncthreads();
    int which = t >> 6;
    int h = (t >> 5) & 1;
    int o = t & 31;
    const float* w  = which ? akw : aqw;
    const float* bb = which ? akb : aqb;
    const float* xp = which ? kp  : qp;
    float bv = bb[h * NDK + o];
    float acc[8];
    for (int r = 0; r < 8; ++r) acc[r] = bv;
    for (int d = 0; d < 128; ++d) {
        float wv = w[((size_t)h * ND + d) * NDK + o];
        #pragma unroll
        for (int r = 0; r < 8; ++r) acc[r] += aks[r][h][d] * wv;
    }
    float* dst = which ? ka : qa;
    for (int r = 0; r < 8; ++r) {
        int g = g0 + r; int b = g / NT; int i = g % NT;
        float val = acc[r] + xp[(size_t)g * ND + h * NDK + o];
        dst[((size_t)(b * 2 + h) * NT + i) * NDK + o] = val;
    }
}

// ---------------------------------------------------------------------------
// Kernel 3: rel-head prep.
// u[b,h,i,d] = sum_o (Xq_r[b,h,i,o]+rel_bias[h,o]) * rel_k_w[h,d,o]
// c[b,h,i]   = sum_o (Xq_r[b,h,i,o]+rel_bias[h,o]) * rel_k_b[h,o]
// ---------------------------------------------------------------------------
__global__ __launch_bounds__(256) void rel_prep_k(
    const float* __restrict__ qp,
    const float* __restrict__ rkw, const float* __restrict__ rkb,
    const float* __restrict__ rbias,
    float* __restrict__ u, float* __restrict__ cb)
{
    __shared__ float qb[8][2][32];
    int t = threadIdx.x;
    int g0 = blockIdx.x * 8;
    for (int idx = t; idx < 8 * 2 * 32; idx += 256) {
        int r = idx >> 6; int h2 = (idx >> 5) & 1; int o = idx & 31;
        int g = g0 + r;
        qb[r][h2][o] = qp[(size_t)g * ND + (2 + h2) * NDK + o] + rbias[h2 * NDK + o];
    }
    __syncthreads();
    int h = t >> 7;
    int d = t & 127;
    float acc[8] = {0, 0, 0, 0, 0, 0, 0, 0};
    for (int o = 0; o < 32; ++o) {
        float wv = rkw[((size_t)h * ND + d) * NDK + o];
        #pragma unroll
        for (int r = 0; r < 8; ++r) acc[r] += qb[r][h][o] * wv;
    }
    for (int r = 0; r < 8; ++r) {
        int g = g0 + r; int b = g / NT; int i = g % NT;
        u[((size_t)(b * 2 + h) * NT + i) * ND + d] = acc[r];
    }
    if (d == 0) {
        for (int r = 0; r < 8; ++r) {
            float cc = 0.0f;
            for (int o = 0; o < 32; ++o) cc += qb[r][h][o] * rkb[h * NDK + o];
            int g = g0 + r; int b = g / NT; int i = g % NT;
            cb[(b * 2 + h) * NT + i] = cc;
        }
    }
}

// ---------------------------------------------------------------------------
// Kernel 4: fused scores + mask + softmax + PV.  One block per (b,h,i).
// Rel streaming: batch-of-5 nontemporal row loads per 32-lane group (20 KB
// in flight per block), 2-step shfl + LDS-partial reduction (short dep chain).
// ---------------------------------------------------------------------------
__global__ __launch_bounds__(256) void attn_core_k(
    const float* __restrict__ qp, const float* __restrict__ kp,
    const float* __restrict__ vp,
    const float* __restrict__ qa, const float* __restrict__ ka,
    const float* __restrict__ u,  const float* __restrict__ cb,
    const int* __restrict__ mask, const float* __restrict__ rel,
    float* __restrict__ xb)
{
    __shared__ float s[256];
    __shared__ float qrow[32];
    __shared__ float redm[4], reds[4];
    __shared__ float xred[256];
    __shared__ float part[200][9];   // padded: (t*9+l)%32 conflict-free
    int t = threadIdx.x;
    int bx = blockIdx.x;
    int i  = bx % NT;
    int bh = bx / NT;
    int h  = bh % NH;
    int b  = bh / NH;
    bool isrel = (h >= 2);
    int hr = h - 2;

    if (t < 32) {
        qrow[t] = isrel ? qp[((size_t)(b * NT + i)) * ND + h * NDK + t]
                        : qa[((size_t)(b * 2 + h) * NT + i) * NDK + t];
    }
    __syncthreads();

    float cval = isrel ? cb[(b * 2 + hr) * NT + i] : 0.0f;
    if (t < NT) {
        const float* krow = isrel ? (kp + ((size_t)(b * NT + t)) * ND + h * NDK)
                                  : (ka + ((size_t)(b * 2 + h) * NT + t) * NDK);
        const float4* k4 = (const float4*)krow;
        const float4* q4 = (const float4*)qrow;
        float acc = cval;
        #pragma unroll
        for (int q = 0; q < 8; ++q) {
            float4 kv = k4[q]; float4 qv = q4[q];
            acc += kv.x * qv.x + kv.y * qv.y + kv.z * qv.z + kv.w * qv.w;
        }
        s[t] = acc;
    } else {
        s[t] = -INFINITY;
    }

    if (isrel) {
        int wid = t >> 6, lane = t & 63, half = lane >> 5, l32 = lane & 31;
        int grp = wid * 2 + half;   // 0..7: which row within each batch-of-8
        const f32x4* u4 = (const f32x4*)(u + ((size_t)(b * 2 + hr) * NT + i) * ND);
        f32x4 ur = u4[l32];
        const float* relbase =
            rel + ((((size_t)hr * NB + b) * NT + i) * (size_t)NT) * ND;
        #pragma unroll 1
        for (int it = 0; it < 25; it += 5) {
            f32x4 rv0, rv1, rv2, rv3, rv4;
            {
                const f32x4* r4;
                r4 = (const f32x4*)(relbase + (size_t)((it + 0) * 8 + grp) * ND);
                rv0 = __builtin_nontemporal_load(r4 + l32);
                r4 = (const f32x4*)(relbase + (size_t)((it + 1) * 8 + grp) * ND);
                rv1 = __builtin_nontemporal_load(r4 + l32);
                r4 = (const f32x4*)(relbase + (size_t)((it + 2) * 8 + grp) * ND);
                rv2 = __builtin_nontemporal_load(r4 + l32);
                r4 = (const f32x4*)(relbase + (size_t)((it + 3) * 8 + grp) * ND);
                rv3 = __builtin_nontemporal_load(r4 + l32);
                r4 = (const f32x4*)(relbase + (size_t)((it + 4) * 8 + grp) * ND);
                rv4 = __builtin_nontemporal_load(r4 + l32);
            }
            #pragma unroll
            for (int n = 0; n < 5; ++n) {
                f32x4 rv = (n == 0) ? rv0 : (n == 1) ? rv1 : (n == 2) ? rv2
                         : (n == 3) ? rv3 : rv4;
                int j = (it + n) * 8 + grp;
                float p = rv.x * ur.x + rv.y * ur.y + rv.z * ur.z + rv.w * ur.w;
                p += __shfl_xor(p, 16, 32);
                p += __shfl_xor(p, 8, 32);
                if (l32 < 8) part[j][l32] = p;   // lanes 0..7 hold 4-lane sums
            }
        }
        __syncthreads();
        if (t < NT) {
            float a2 = part[t][0] + part[t][1] + part[t][2] + part[t][3]
                     + part[t][4] + part[t][5] + part[t][6] + part[t][7];
            s[t] += a2;
        }
    }
    __syncthreads();

    // scale then mask (matches reference order)
    if (t < NT) {
        float val = s[t] * 0.17677669529663687f;   // 1/sqrt(32)
        if (mask[((size_t)b * NT + i) * NT + t] == 0) val = -1.0e9f;
        s[t] = val;
    }
    __syncthreads();

    // softmax over 256 slots (pad = -inf -> exp 0)
    float sv = s[t];
    float m = sv;
    #pragma unroll
    for (int dd = 32; dd >= 1; dd >>= 1) m = fmaxf(m, __shfl_xor(m, dd, 64));
    if ((t & 63) == 0) redm[t >> 6] = m;
    __syncthreads();
    m = fmaxf(fmaxf(redm[0], redm[1]), fmaxf(redm[2], redm[3]));
    float e = expf(sv - m);
    float ssum = e;
    #pragma unroll
    for (int dd = 32; dd >= 1; dd >>= 1) ssum += __shfl_xor(ssum, dd, 64);
    if ((t & 63) == 0) reds[t >> 6] = ssum;
    __syncthreads();
    float tot = reds[0] + reds[1] + reds[2] + reds[3];
    s[t] = e / tot;
    __syncthreads();

    // PV: x[o] = sum_j p[j] * v[b, j, h*32+o]
    int o = t & 31, g = t >> 5;
    float acc2 = 0.0f;
    const float* vb = vp + (size_t)b * NT * ND + h * NDK + o;
    for (int j = g; j < NT; j += 8) acc2 += s[j] * vb[(size_t)j * ND];
    xred[t] = acc2;
    __syncthreads();
    if (t < 32) {
        float r = 0.0f;
        #pragma unroll
        for (int g2 = 0; g2 < 8; ++g2) r += xred[g2 * 32 + t];
        xb[((size_t)(b * NT + i)) * ND + h * NDK + t] = r;
    }
}

// ---------------------------------------------------------------------------
// Kernel 5: output projection.  out = xb @ Wo + bo.
// ---------------------------------------------------------------------------
__global__ __launch_bounds__(128) void out_proj_k(
    const float* __restrict__ xb, const float* __restrict__ Wo,
    const float* __restrict__ bo, float* __restrict__ out)
{
    __shared__ float xs[4][128];
    int t = threadIdx.x;
    int g0 = blockIdx.x * 4;
    for (int r = 0; r < 4; ++r) xs[r][t] = xb[(size_t)(g0 + r) * ND + t];
    __syncthreads();
    float bb = bo[t];
    float acc[4];
    for (int r = 0; r < 4; ++r) acc[r] = bb;
    for (int d = 0; d < 128; ++d) {
        float wv = Wo[d * ND + t];
        #pragma unroll
        for (int r = 0; r < 4; ++r) acc[r] += xs[r][d] * wv;
    }
    for (int r = 0; r < 4; ++r) out[(size_t)(g0 + r) * ND + t] = acc[r];
}

// ---------------------------------------------------------------------------
extern "C" void kernel_launch(void* const* d_in, const int* in_sizes, int n_in,
                              void* d_out, int out_size, void* d_ws, size_t ws_size,
                              hipStream_t stream)
{
    const float* query = (const float*)d_in[0];
    const float* key_  = (const float*)d_in[1];
    const float* value = (const float*)d_in[2];
    const int*   mask  = (const int*)  d_in[3];
    const float* rel   = (const float*)d_in[4];
    const float* absk  = (const float*)d_in[5];
    // d_in[6] = layer (unused by reference)
    const float* Wq = (const float*)d_in[7];
    const float* bq = (const float*)d_in[8];
    const float* Wk = (const float*)d_in[9];
    const float* bk = (const float*)d_in[10];
    const float* Wv = (const float*)d_in[11];
    const float* bv = (const float*)d_in[12];
    const float* aqw = (const float*)d_in[13];
    const float* aqb = (const float*)d_in[14];
    const float* akw = (const float*)d_in[15];
    const float* akb = (const float*)d_in[16];
    const float* rkw = (const float*)d_in[17];
    const float* rkb = (const float*)d_in[18];
    const float* rbias = (const float*)d_in[19];
    const float* Wo = (const float*)d_in[20];
    const float* bo = (const float*)d_in[21];
    float* out = (float*)d_out;

    // workspace layout (floats)
    float* qp = (float*)d_ws;          // 409600  (B,T,D)
    float* kp = qp + 409600;           // 409600
    float* vp = kp + 409600;           // 409600
    float* qa = vp + 409600;           // 204800  (B,2,T,32)
    float* ka = qa + 204800;           // 204800
    float* ub = ka + 204800;           // 819200  (B,2,T,128)
    float* cb = ub + 819200;           // 6400    (B,2,T)
    float* xb = cb + 6400;             // 409600  (B,T,D)

    qkv_proj_k<<<NB * NT / 4, 128, 0, stream>>>(query, key_, value,
                                                Wq, bq, Wk, bk, Wv, bv,
                                                qp, kp, vp);
    abs_prep_k<<<NB * NT / 8, 128, 0, stream>>>(absk, aqw, aqb, akw, akb,
                                                qp, kp, qa, ka);
    rel_prep_k<<<NB * NT / 8, 256, 0, stream>>>(qp, rkw, rkb, rbias, ub, cb);
    attn_core_k<<<NB * NH * NT, 256, 0, stream>>>(qp, kp, vp, qa, ka, ub, cb,
                                                  mask, rel, xb);
    out_proj_k<<<NB * NT / 4, 128, 0, stream>>>(xb, Wo, bo, out);
}